// Round 1
// baseline (565.812 us; speedup 1.0000x reference)
//
#include <hip/hip_runtime.h>
#include <hip/hip_bf16.h>

#define NB    128
#define NSIG  12
#define KLEN  4096
#define NF    2049          // rfft bins
#define NFP   2080          // padded (65*32)
#define NTAU  257
#define NTAUP 320           // padded tau rows (20*16)
#define NROW  (NB*NSIG)
#define TBL_ELEMS (NTAUP*NFP)

typedef short short8_t __attribute__((ext_vector_type(8)));
typedef float floatx4  __attribute__((ext_vector_type(4)));

__device__ __forceinline__ unsigned short f2bf(float f) {
  union { float f; unsigned u; } v; v.f = f;
  unsigned r = v.u + 0x7FFFu + ((v.u >> 16) & 1u);   // RNE
  return (unsigned short)(r >> 16);
}
__device__ __forceinline__ float bf2f(unsigned short h) {
  union { unsigned u; float f; } v; v.u = ((unsigned)h) << 16;
  return v.f;
}

// ---------------- Stage 1: FFT + PHAT normalize -> bf16 unit spectrum ----------------
__global__ __launch_bounds__(256) void k_fft_phat(const float* __restrict__ x,
                                                  unsigned short* __restrict__ Xr,
                                                  unsigned short* __restrict__ Xi) {
  __shared__ float re[KLEN];
  __shared__ float im[KLEN];
  const int row = blockIdx.x;          // b*12+n
  const int tid = threadIdx.x;
  const float* xr = x + (size_t)row * KLEN;

  // coalesced float4 loads, bit-reversed scatter into LDS (imag = 0)
  #pragma unroll
  for (int q = 0; q < 4; q++) {
    float4 v = ((const float4*)xr)[tid * 4 + q];
    #pragma unroll
    for (int u = 0; u < 4; u++) {
      int t  = tid * 16 + q * 4 + u;
      int br = __brev((unsigned)t) >> 20;
      re[br] = (&v.x)[u];
      im[br] = 0.f;
    }
  }
  __syncthreads();

  // in-place radix-2 DIT, forward DFT (w = e^{-2pi i j/len})
  for (int s = 1; s <= 12; s++) {
    const int half = 1 << (s - 1);
    const float ang0 = -6.2831853071795864f / (float)(1 << s);
    for (int i = tid; i < 2048; i += 256) {
      const int j   = i & (half - 1);
      const int pos = ((i >> (s - 1)) << s) + j;
      float sn, cs;
      __sincosf(ang0 * (float)j, &sn, &cs);
      float ur = re[pos],       ui = im[pos];
      float wr = re[pos + half], wi = im[pos + half];
      float vr = wr * cs - wi * sn;
      float vi = wr * sn + wi * cs;
      re[pos]        = ur + vr;  im[pos]        = ui + vi;
      re[pos + half] = ur - vr;  im[pos + half] = ui - vi;
    }
    __syncthreads();
  }

  // PHAT normalize, store bins 0..2048, zero-pad to 2080
  unsigned short* Xrr = Xr + (size_t)row * NFP;
  unsigned short* Xii = Xi + (size_t)row * NFP;
  for (int f = tid; f < NFP; f += 256) {
    float a = 0.f, bb = 0.f;
    if (f < NF) {
      float rr = re[f], ii = im[f];
      float mag = sqrtf(rr * rr + ii * ii) + 1e-12f;   // matches reference EPS
      a  = rr / mag;
      bb = ii / mag;
    }
    Xrr[f] = f2bf(a);
    Xii[f] = f2bf(bb);
  }
}

// ---------------- Stage 2: irfft lag tables (tau-major for B-fragments) ----------------
// C[o][f] = w_f cos(2pi f t_o / K), S[o][f] = -w_f sin(...), t_o = o<=128 ? o : o+3839
__global__ __launch_bounds__(256) void k_tables(unsigned short* __restrict__ C,
                                                unsigned short* __restrict__ S) {
  int e = blockIdx.x * 256 + threadIdx.x;
  if (e >= TBL_ELEMS) return;
  int tau = e / NFP;
  int f   = e - tau * NFP;
  float cv = 0.f, sv = 0.f;
  if (tau < NTAU && f < NF) {
    float wgt = (f == 0 || f == KLEN / 2) ? (1.0f / KLEN) : (2.0f / KLEN);
    int teff = (tau <= 128) ? tau : (tau + (KLEN - NTAU));   // negative lags
    int r = (f * teff) & (KLEN - 1);                         // exact angle mod 2pi
    float ang = (float)r * (6.2831853071795864f / KLEN);
    float sn, cs;
    __sincosf(ang, &sn, &cs);
    cv =  wgt * cs;
    sv = -wgt * sn;
  }
  C[e] = f2bf(cv);
  S[e] = f2bf(sv);
}

// ---------------- Stage 3: out[p, o] = Gr·C + Gi·S via bf16 MFMA ----------------
// grid (2, 128): mb = half of the 144 pairs (72 rows), b = batch
// block tile: M=80 (5 frags, rows 72 used), N=320 (20 frags / 4 waves = 5 each), K-step 32
__global__ __launch_bounds__(256) void k_corr(const unsigned short* __restrict__ Xr,
                                              const unsigned short* __restrict__ Xi,
                                              const unsigned short* __restrict__ Tbl, // [2][320][2080]
                                              float* __restrict__ out) {
  __shared__ float Xs[2][NSIG][32];
  __shared__ alignas(16) unsigned short Asm_[80 * 40];    // row stride 40 bf16 = 80B
  __shared__ alignas(16) unsigned short Bsm_[320 * 40];
  const int b   = blockIdx.y;
  const int mb  = blockIdx.x;
  const int tid = threadIdx.x;
  const int w    = tid >> 6;
  const int lane = tid & 63;

  floatx4 acc[5][5];
  #pragma unroll
  for (int i = 0; i < 5; i++)
    #pragma unroll
    for (int j = 0; j < 5; j++)
      acc[i][j] = (floatx4){0.f, 0.f, 0.f, 0.f};

  const unsigned short* XrB = Xr + (size_t)b * NSIG * NFP;
  const unsigned short* XiB = Xi + (size_t)b * NSIG * NFP;
  const int arow = lane & 15;
  const int aoff = (lane >> 4) << 3;

  for (int step = 0; step < 130; step++) {
    const int phi = (step >= 65) ? 1 : 0;
    const int f0  = (step - 65 * phi) * 32;
    __syncthreads();   // previous iteration's LDS reads done

    // stage X chunk (bf16 -> f32) and B tile (global bf16 -> LDS)
    for (int e = tid; e < NSIG * 32; e += 256) {
      int n = e >> 5, k = e & 31;
      Xs[0][n][k] = bf2f(XrB[n * NFP + f0 + k]);
      Xs[1][n][k] = bf2f(XiB[n * NFP + f0 + k]);
    }
    const unsigned short* Tp = Tbl + (size_t)phi * TBL_ELEMS;
    for (int e = tid; e < 1280; e += 256) {
      int tau = e >> 2, ko = (e & 3) << 3;
      uint4 v = *(const uint4*)(Tp + (size_t)tau * NFP + f0 + ko);
      *(uint4*)(&Bsm_[tau * 40 + ko]) = v;
    }
    __syncthreads();

    // A tile: G[p][k] for this phase (Gr = xr·xr'+xi·xi', Gi = xi·xr'-xr·xi')
    for (int e = tid; e < 80 * 32; e += 256) {
      int rl = e >> 5, k = e & 31;
      float val = 0.f;
      if (rl < 72) {
        int p = mb * 72 + rl;
        int n = p / 12;
        int m = p - n * 12;
        float xrn = Xs[0][n][k], xin = Xs[1][n][k];
        float xrm = Xs[0][m][k], xim = Xs[1][m][k];
        val = phi ? (xin * xrm - xrn * xim) : (xrn * xrm + xin * xim);
      }
      Asm_[rl * 40 + k] = f2bf(val);
    }
    __syncthreads();

    // MFMA: A lane row = lane&15, k = (lane>>4)*8+j ; B lane col = lane&15, same k
    short8_t aF[5];
    #pragma unroll
    for (int mi = 0; mi < 5; mi++)
      aF[mi] = *(const short8_t*)(&Asm_[(mi * 16 + arow) * 40 + aoff]);
    #pragma unroll
    for (int ni = 0; ni < 5; ni++) {
      const int ct = ni * 4 + w;
      short8_t bF = *(const short8_t*)(&Bsm_[(ct * 16 + arow) * 40 + aoff]);
      #pragma unroll
      for (int mi = 0; mi < 5; mi++)
        acc[mi][ni] = __builtin_amdgcn_mfma_f32_16x16x32_bf16(aF[mi], bF, acc[mi][ni], 0, 0, 0);
    }
  }

  // epilogue: D col = lane&15 (tau), row = (lane>>4)*4 + reg
  const int rbase = (lane >> 4) << 2;
  #pragma unroll
  for (int ni = 0; ni < 5; ni++) {
    const int tau = (ni * 4 + w) * 16 + (lane & 15);
    if (tau >= NTAU) continue;
    #pragma unroll
    for (int mi = 0; mi < 5; mi++) {
      #pragma unroll
      for (int r = 0; r < 4; r++) {
        int rl = mi * 16 + rbase + r;
        if (rl < 72) {
          int p = mb * 72 + rl;
          out[((size_t)b * 144 + p) * NTAU + tau] = acc[mi][ni][r];
        }
      }
    }
  }
}

extern "C" void kernel_launch(void* const* d_in, const int* in_sizes, int n_in,
                              void* d_out, int out_size, void* d_ws, size_t ws_size,
                              hipStream_t stream) {
  const float* x = (const float*)d_in[0];
  float* out = (float*)d_out;

  // ws layout (15.45 MB total): [C tbl][S tbl][Xr bf16][Xi bf16]
  unsigned short* Ct = (unsigned short*)d_ws;                 // TBL_ELEMS
  unsigned short* St = Ct + TBL_ELEMS;                        // TBL_ELEMS
  unsigned short* Xr = St + TBL_ELEMS;                        // NROW*NFP
  unsigned short* Xi = Xr + (size_t)NROW * NFP;               // NROW*NFP

  k_fft_phat<<<NROW, 256, 0, stream>>>(x, Xr, Xi);
  k_tables<<<(TBL_ELEMS + 255) / 256, 256, 0, stream>>>(Ct, St);
  k_corr<<<dim3(2, NB), 256, 0, stream>>>(Xr, Xi, Ct, out);
}

// Round 3
// 261.287 us; speedup vs baseline: 2.1655x; 2.1655x over previous
//
#include <hip/hip_runtime.h>
#include <hip/hip_bf16.h>

#define NB    128
#define NSIG  12
#define KLEN  4096
#define NF    2049          // rfft bins
#define NFP   2080          // padded (65*32)
#define NTAU  257
#define NTAUP 320           // padded tau rows (20*16)
#define NROW  (NB*NSIG)
#define TBL_ELEMS (NTAUP*NFP)
#define OUT_ELEMS (NB*144*NTAU)

typedef short short8_t __attribute__((ext_vector_type(8)));
typedef float floatx4  __attribute__((ext_vector_type(4)));

__device__ __forceinline__ unsigned short f2bf(float f) {
  union { float f; unsigned u; } v; v.f = f;
  unsigned r = v.u + 0x7FFFu + ((v.u >> 16) & 1u);   // RNE
  return (unsigned short)(r >> 16);
}
__device__ __forceinline__ float bf2f(unsigned short h) {
  union { unsigned u; float f; } v; v.u = ((unsigned)h) << 16;
  return v.f;
}

// ---------------- Stage 1: FFT + PHAT normalize -> bf16 unit spectrum ----------------
__global__ __launch_bounds__(512) void k_fft_phat(const float* __restrict__ x,
                                                  unsigned short* __restrict__ Xr,
                                                  unsigned short* __restrict__ Xi) {
  __shared__ float re[KLEN];
  __shared__ float im[KLEN];
  const int row = blockIdx.x;          // b*12+n
  const int tid = threadIdx.x;
  const float* xr = x + (size_t)row * KLEN;

  // coalesced float4 loads, bit-reversed scatter into LDS (imag = 0)
  #pragma unroll
  for (int q = 0; q < 2; q++) {
    float4 v = ((const float4*)xr)[tid * 2 + q];
    #pragma unroll
    for (int u = 0; u < 4; u++) {
      int t  = tid * 8 + q * 4 + u;
      int br = __brev((unsigned)t) >> 20;
      re[br] = (&v.x)[u];
      im[br] = 0.f;
    }
  }
  __syncthreads();

  // in-place radix-2 DIT, forward DFT (w = e^{-2pi i j/len})
  for (int s = 1; s <= 12; s++) {
    const int half = 1 << (s - 1);
    const float ang0 = -6.2831853071795864f / (float)(1 << s);
    for (int i = tid; i < 2048; i += 512) {
      const int j   = i & (half - 1);
      const int pos = ((i >> (s - 1)) << s) + j;
      float sn, cs;
      __sincosf(ang0 * (float)j, &sn, &cs);
      float ur = re[pos],       ui = im[pos];
      float wr = re[pos + half], wi = im[pos + half];
      float vr = wr * cs - wi * sn;
      float vi = wr * sn + wi * cs;
      re[pos]        = ur + vr;  im[pos]        = ui + vi;
      re[pos + half] = ur - vr;  im[pos + half] = ui - vi;
    }
    __syncthreads();
  }

  // PHAT normalize, store bins 0..2048, zero-pad to 2080
  unsigned short* Xrr = Xr + (size_t)row * NFP;
  unsigned short* Xii = Xi + (size_t)row * NFP;
  for (int f = tid; f < NFP; f += 512) {
    float a = 0.f, bb = 0.f;
    if (f < NF) {
      float rr = re[f], ii = im[f];
      float mag = sqrtf(rr * rr + ii * ii) + 1e-12f;   // matches reference EPS
      a  = rr / mag;
      bb = ii / mag;
    }
    Xrr[f] = f2bf(a);
    Xii[f] = f2bf(bb);
  }
}

// ---------------- Stage 2: irfft lag tables (tau-major for B-fragments) ----------------
// C[o][f] = w_f cos(2pi f t_o / K), S[o][f] = -w_f sin(...), t_o = o<=128 ? o : o+3839
__global__ __launch_bounds__(256) void k_tables(unsigned short* __restrict__ C,
                                                unsigned short* __restrict__ S) {
  int e = blockIdx.x * 256 + threadIdx.x;
  if (e >= TBL_ELEMS) return;
  int tau = e / NFP;
  int f   = e - tau * NFP;
  float cv = 0.f, sv = 0.f;
  if (tau < NTAU && f < NF) {
    float wgt = (f == 0 || f == KLEN / 2) ? (1.0f / KLEN) : (2.0f / KLEN);
    int teff = (tau <= 128) ? tau : (tau + (KLEN - NTAU));   // negative lags
    int r = (f * teff) & (KLEN - 1);                         // exact angle mod 2pi
    float ang = (float)r * (6.2831853071795864f / KLEN);
    float sn, cs;
    __sincosf(ang, &sn, &cs);
    cv =  wgt * cs;
    sv = -wgt * sn;
  }
  C[e] = f2bf(cv);
  S[e] = f2bf(sv);
}

// ---------------- Stage 3: partial[z][p,o] = (z?Gi·S:Gr·C) via bf16 MFMA ----------------
// grid (2, 128, 2): mb = half of pairs (72 rows), b = batch, z = phase (real/imag)
// block: 512 thr = 8 waves (2M x 4N). tile M=96 (rows 72 used), N=320, K-step 32, 65 steps
template <bool ATOMIC>
__global__ __launch_bounds__(512) void k_corr(const unsigned short* __restrict__ Xr,
                                              const unsigned short* __restrict__ Xi,
                                              const unsigned short* __restrict__ Tbl, // [2][320][2080]
                                              float* __restrict__ P) { // [2][128][144][257] or out
  __shared__ float Xs[2][NSIG][32];
  __shared__ alignas(16) unsigned short Asm_[96 * 40];    // row stride 40 bf16 = 80B
  __shared__ alignas(16) unsigned short Bsm_[320 * 40];
  const int b   = blockIdx.y;
  const int mb  = blockIdx.x;
  const int phi = blockIdx.z;
  const int tid = threadIdx.x;
  const int w    = tid >> 6;
  const int wm   = w >> 2;           // 0..1  (M half)
  const int wn   = w & 3;            // 0..3  (N quarter)
  const int lane = tid & 63;

  floatx4 acc[3][5];
  #pragma unroll
  for (int i = 0; i < 3; i++)
    #pragma unroll
    for (int j = 0; j < 5; j++)
      acc[i][j] = (floatx4){0.f, 0.f, 0.f, 0.f};

  const unsigned short* XrB = Xr + (size_t)b * NSIG * NFP;
  const unsigned short* XiB = Xi + (size_t)b * NSIG * NFP;
  const unsigned short* Tp  = Tbl + (size_t)phi * TBL_ELEMS;
  const int arow = lane & 15;
  const int aoff = (lane >> 4) << 3;

  for (int step = 0; step < 65; step++) {
    const int f0 = step * 32;
    __syncthreads();   // previous iteration's LDS reads done

    // stage X chunk (bf16, uint4 = 8 elems) and B tile (global bf16 -> LDS)
    if (tid < 96) {
      int c = tid >> 2;                 // 0..23
      int part = (c >= 12);
      int n = c - part * 12;
      int k8 = (tid & 3) << 3;
      const unsigned short* src = (part ? XiB : XrB) + n * NFP + f0 + k8;
      uint4 v = *(const uint4*)src;
      const unsigned short* hs = (const unsigned short*)&v;
      #pragma unroll
      for (int u = 0; u < 8; u++) Xs[part][n][k8 + u] = bf2f(hs[u]);
    }
    #pragma unroll
    for (int ee = 0; ee < 3; ee++) {
      int e = tid + ee * 512;
      if (e < 1280) {
        int tau = e >> 2, ko = (e & 3) << 3;
        uint4 v = *(const uint4*)(Tp + (size_t)tau * NFP + f0 + ko);
        *(uint4*)(&Bsm_[tau * 40 + ko]) = v;
      }
    }
    __syncthreads();

    // A tile: G[p][k] this phase (z=0: xr·xr'+xi·xi', z=1: xi·xr'-xr·xi'), float2 at a time
    #pragma unroll
    for (int ee = 0; ee < 3; ee++) {
      int e = tid + ee * 512;           // 0..1535
      int rl = e >> 4, kk = (e & 15) << 1;
      unsigned pk = 0;
      if (rl < 72) {
        int p = mb * 72 + rl;
        int n = p / 12;
        int m = p - n * 12;
        float2 xrn = *(const float2*)&Xs[0][n][kk];
        float2 xin = *(const float2*)&Xs[1][n][kk];
        float2 xrm = *(const float2*)&Xs[0][m][kk];
        float2 xim = *(const float2*)&Xs[1][m][kk];
        float v0, v1;
        if (phi) { v0 = xin.x * xrm.x - xrn.x * xim.x; v1 = xin.y * xrm.y - xrn.y * xim.y; }
        else     { v0 = xrn.x * xrm.x + xin.x * xim.x; v1 = xrn.y * xrm.y + xin.y * xim.y; }
        pk = (unsigned)f2bf(v0) | ((unsigned)f2bf(v1) << 16);
      }
      *(unsigned*)(&Asm_[rl * 40 + kk]) = pk;
    }
    __syncthreads();

    // MFMA: A lane row = lane&15, k = (lane>>4)*8+j ; B lane col = lane&15, same k
    short8_t aF[3];
    #pragma unroll
    for (int mi = 0; mi < 3; mi++)
      aF[mi] = *(const short8_t*)(&Asm_[(wm * 48 + mi * 16 + arow) * 40 + aoff]);
    #pragma unroll
    for (int ni = 0; ni < 5; ni++) {
      const int ct = ni * 4 + wn;
      short8_t bF = *(const short8_t*)(&Bsm_[(ct * 16 + arow) * 40 + aoff]);
      #pragma unroll
      for (int mi = 0; mi < 3; mi++)
        acc[mi][ni] = __builtin_amdgcn_mfma_f32_16x16x32_bf16(aF[mi], bF, acc[mi][ni], 0, 0, 0);
    }
  }

  // epilogue: D col = lane&15 (tau), row = (lane>>4)*4 + reg
  float* Pz = ATOMIC ? P : (P + (size_t)phi * OUT_ELEMS);
  const int rbase = (lane >> 4) << 2;
  #pragma unroll
  for (int ni = 0; ni < 5; ni++) {
    const int tau = (ni * 4 + wn) * 16 + (lane & 15);
    if (tau >= NTAU) continue;
    #pragma unroll
    for (int mi = 0; mi < 3; mi++) {
      #pragma unroll
      for (int r = 0; r < 4; r++) {
        int rl = wm * 48 + mi * 16 + rbase + r;
        if (rl < 72) {
          int p = mb * 72 + rl;
          size_t idx = ((size_t)b * 144 + p) * NTAU + tau;
          if (ATOMIC) atomicAdd(&Pz[idx], acc[mi][ni][r]);
          else        Pz[idx] = acc[mi][ni][r];
        }
      }
    }
  }
}

// ---------------- Stage 4: out = P0 + P1 ----------------
__global__ __launch_bounds__(256) void k_sum(const float4* __restrict__ P0,
                                             const float4* __restrict__ P1,
                                             float4* __restrict__ out) {
  int i = blockIdx.x * 256 + threadIdx.x;
  if (i < OUT_ELEMS / 4) {
    float4 a = P0[i], b = P1[i];
    out[i] = make_float4(a.x + b.x, a.y + b.y, a.z + b.z, a.w + b.w);
  }
}

extern "C" void kernel_launch(void* const* d_in, const int* in_sizes, int n_in,
                              void* d_out, int out_size, void* d_ws, size_t ws_size,
                              hipStream_t stream) {
  const float* x = (const float*)d_in[0];
  float* out = (float*)d_out;

  // ws layout: [C tbl][S tbl][Xr bf16][Xi bf16][P0 f32][P1 f32]
  unsigned short* Ct = (unsigned short*)d_ws;                 // TBL_ELEMS
  unsigned short* St = Ct + TBL_ELEMS;                        // TBL_ELEMS
  unsigned short* Xr = St + TBL_ELEMS;                        // NROW*NFP
  unsigned short* Xi = Xr + (size_t)NROW * NFP;               // NROW*NFP
  float* Pp = (float*)(Xi + (size_t)NROW * NFP);              // 2*OUT_ELEMS
  const size_t base_bytes = (size_t)(2 * TBL_ELEMS + 2 * NROW * NFP) * 2;
  const size_t need = base_bytes + (size_t)2 * OUT_ELEMS * 4;

  k_fft_phat<<<NROW, 512, 0, stream>>>(x, Xr, Xi);
  k_tables<<<(TBL_ELEMS + 255) / 256, 256, 0, stream>>>(Ct, St);

  if (ws_size >= need) {
    k_corr<false><<<dim3(2, NB, 2), 512, 0, stream>>>(Xr, Xi, Ct, Pp);
    k_sum<<<(OUT_ELEMS / 4 + 255) / 256, 256, 0, stream>>>((const float4*)Pp,
                                                           (const float4*)(Pp + OUT_ELEMS),
                                                           (float4*)out);
  } else {
    hipMemsetAsync(d_out, 0, (size_t)out_size * 4, stream);
    k_corr<true><<<dim3(2, NB, 2), 512, 0, stream>>>(Xr, Xi, Ct, out);
  }
}

// Round 5
// 194.131 us; speedup vs baseline: 2.9146x; 1.3459x over previous
//
#include <hip/hip_runtime.h>
#include <hip/hip_bf16.h>

#define NB    128
#define NSIG  12
#define KLEN  4096
#define NF    2049          // rfft bins
#define NFP   2080          // padded (65*32)
#define NTAU  257
#define NTAUH 129           // taus 0..128 computed; o>=129 filled by symmetry
#define NROW  (NB*NSIG)
#define NSLICE 65           // K slices of 32
#define BROWS 144           // B tile rows (taus 0..128 live, 129..143 zero)
#define TBLN  (NSLICE*BROWS*32)   // shorts per phase table
#define PELEMS ((size_t)NB*144*NTAUH)
#define OUT_ELEMS (NB*144*NTAU)

typedef short short8_t __attribute__((ext_vector_type(8)));
typedef float floatx4  __attribute__((ext_vector_type(4)));

__device__ __forceinline__ unsigned short f2bf(float f) {
  union { float f; unsigned u; } v; v.f = f;
  unsigned r = v.u + 0x7FFFu + ((v.u >> 16) & 1u);   // RNE
  return (unsigned short)(r >> 16);
}
__device__ __forceinline__ float ubits(unsigned u) {
  union { unsigned u; float f; } v; v.u = u; return v.f;
}
__device__ __forceinline__ float bf2f(unsigned short h) { return ubits(((unsigned)h) << 16); }

// async global(bf16 chunk of 16B) -> LDS; dest = wave-uniform base + lane*16
__device__ __forceinline__ void gload16(const unsigned short* g, unsigned short* l) {
  __builtin_amdgcn_global_load_lds((const __attribute__((address_space(1))) unsigned int*)g,
                                   (__attribute__((address_space(3))) unsigned int*)l, 16, 0, 0);
}

// ---------------- Stage 1: FFT + PHAT normalize -> bf16 unit spectrum ----------------
__global__ __launch_bounds__(512) void k_fft_phat(const float* __restrict__ x,
                                                  unsigned short* __restrict__ Xr,
                                                  unsigned short* __restrict__ Xi) {
  __shared__ float re[KLEN];
  __shared__ float im[KLEN];
  const int row = blockIdx.x;          // b*12+n
  const int tid = threadIdx.x;
  const float* xr = x + (size_t)row * KLEN;

  #pragma unroll
  for (int q = 0; q < 2; q++) {
    float4 v = ((const float4*)xr)[tid * 2 + q];
    #pragma unroll
    for (int u = 0; u < 4; u++) {
      int t  = tid * 8 + q * 4 + u;
      int br = __brev((unsigned)t) >> 20;
      re[br] = (&v.x)[u];
      im[br] = 0.f;
    }
  }
  __syncthreads();

  for (int s = 1; s <= 12; s++) {
    const int half = 1 << (s - 1);
    const float ang0 = -6.2831853071795864f / (float)(1 << s);
    for (int i = tid; i < 2048; i += 512) {
      const int j   = i & (half - 1);
      const int pos = ((i >> (s - 1)) << s) + j;
      float sn, cs;
      __sincosf(ang0 * (float)j, &sn, &cs);
      float ur = re[pos],       ui = im[pos];
      float wr = re[pos + half], wi = im[pos + half];
      float vr = wr * cs - wi * sn;
      float vi = wr * sn + wi * cs;
      re[pos]        = ur + vr;  im[pos]        = ui + vi;
      re[pos + half] = ur - vr;  im[pos + half] = ui - vi;
    }
    __syncthreads();
  }

  unsigned short* Xrr = Xr + (size_t)row * NFP;
  unsigned short* Xii = Xi + (size_t)row * NFP;
  for (int f = tid; f < NFP; f += 512) {
    float a = 0.f, bb = 0.f;
    if (f < NF) {
      float rr = re[f], ii = im[f];
      float mag = sqrtf(rr * rr + ii * ii) + 1e-12f;
      a  = rr / mag;
      bb = ii / mag;
    }
    Xrr[f] = f2bf(a);
    Xii[f] = f2bf(bb);
  }
}

// ---------------- Stage 2: lag tables, slice-tiled + XOR-swizzled chunk layout ----------
// Tbl[ph][s][row][chp][j] holds logical (row, chl=chp^((row>>1)&3)) value:
//   f = s*32 + chl*8 + j, tau = row;  ph0: w*cos(2pi f tau/K), ph1: -w*sin(...)
__global__ __launch_bounds__(256) void k_tables(unsigned short* __restrict__ Tbl) {
  int e = blockIdx.x * 256 + threadIdx.x;
  if (e >= 2 * TBLN) return;
  int ph = e / TBLN;
  int r  = e - ph * TBLN;
  int s  = r / (BROWS * 32);
  int r2 = r - s * (BROWS * 32);
  int row = r2 >> 5;
  int q   = r2 & 31;
  int chp = q >> 3;
  int j   = q & 7;
  int chl = chp ^ ((row >> 1) & 3);
  int f   = s * 32 + chl * 8 + j;
  float val = 0.f;
  if (row <= 128 && f <= 2048) {
    float wgt = (f == 0 || f == KLEN / 2) ? (1.0f / KLEN) : (2.0f / KLEN);
    int rr = (f * row) & (KLEN - 1);
    float ang = (float)rr * (6.2831853071795864f / KLEN);
    float sn, cs;
    __sincosf(ang, &sn, &cs);
    val = ph ? (-wgt * sn) : (wgt * cs);
  }
  Tbl[e] = f2bf(val);
}

// ---------------- Stage 3: P[z][b][p][tau 0..128] = (z?Gi·S:Gr·C), pipelined MFMA -------
// grid (2, 128, 2): mb = pair half (72 rows), b, z = phase. 512 thr = 8 waves (2M x 4N).
// tile M=96 (72 live), N=144 (9 frags; ct=ni*4+wn, skip ct>8), K-step 32, 65 steps.
__global__ __launch_bounds__(512, 4) void k_corr(const unsigned short* __restrict__ Xr,
                                                 const unsigned short* __restrict__ Xi,
                                                 const unsigned short* __restrict__ Tbl,
                                                 float* __restrict__ P) {
  __shared__ alignas(16) unsigned short Xs[2][1024];      // [part2][n12][k32] = 768 used + pad
  __shared__ alignas(16) unsigned short Bs[2][BROWS * 32];// 576 chunks, swizzled layout
  __shared__ alignas(16) unsigned short Asm_[96 * 40];    // row stride 40 shorts = 80B

  const int b    = blockIdx.y;
  const int mb   = blockIdx.x;
  const int phi  = blockIdx.z;
  const int tid  = threadIdx.x;
  const int w    = tid >> 6;
  const int wm   = w >> 2;            // 0..1
  const int wn   = w & 3;             // 0..3
  const int lane = tid & 63;
  const int arow = lane & 15;
  const int g    = lane >> 4;         // 0..3 (k chunk)
  const int aoff = g << 3;

  floatx4 acc[3][3];
  #pragma unroll
  for (int i = 0; i < 3; i++)
    #pragma unroll
    for (int j = 0; j < 3; j++)
      acc[i][j] = (floatx4){0.f, 0.f, 0.f, 0.f};

  const unsigned short* XrB = Xr + (size_t)b * NSIG * NFP;
  const unsigned short* XiB = Xi + (size_t)b * NSIG * NFP;
  const unsigned short* Tp  = Tbl + (size_t)phi * TBLN;

  auto STAGE = [&](int sl, int nb) {
    const unsigned short* Tsl = Tp + (size_t)sl * (BROWS * 32);
    const int f0n = sl * 32;
    {
      int c = (w << 6) + lane;   // 0..511
      gload16(Tsl + ((c >> 2) << 5) + ((c & 3) << 3), &Bs[nb][(w << 6) * 8]);
    }
    if (w == 0) {                // B chunks 512..575
      int c2 = 512 + lane;
      gload16(Tsl + ((c2 >> 2) << 5) + ((c2 & 3) << 3), &Bs[nb][512 * 8]);
    } else if (w == 1) {         // X chunks 0..63 (Xr n0..11, Xi n0..3)
      int part = lane >= 48;
      int cc = lane - part * 48;
      const unsigned short* src = (part ? XiB : XrB) + (cc >> 2) * NFP + f0n + ((cc & 3) << 3);
      gload16(src, &Xs[nb][0]);
    } else if (w == 2) {         // X chunks 64..95 (Xi n4..11)
      if (lane < 32) {
        int cc = 16 + lane;      // Xi chunk index 16..47
        gload16(XiB + (cc >> 2) * NFP + f0n + ((cc & 3) << 3), &Xs[nb][64 * 8]);
      }
    }
  };

  // prologue: stage slice 0 into buf 0
  STAGE(0, 0);
  asm volatile("s_waitcnt vmcnt(0)" ::: "memory");
  __builtin_amdgcn_s_barrier();
  asm volatile("" ::: "memory");

  for (int t = 0; t < NSLICE; t++) {
    const int cur = t & 1;
    if (t + 1 < NSLICE) STAGE(t + 1, cur ^ 1);

    // A tile: G[p][k] (z=0: xr·xr'+xi·xi', z=1: xi·xr'-xr·xi'), bf16 pairs
    #pragma unroll
    for (int ee = 0; ee < 3; ee++) {
      int e  = tid + ee * 512;        // 0..1535
      int rl = e >> 4;
      int kk = (e & 15) << 1;
      unsigned pk = 0;
      if (rl < 72) {
        int p = mb * 72 + rl;
        int n = p / 12;
        int m = p - n * 12;
        unsigned urn = *(const unsigned*)&Xs[cur][n * 32 + kk];
        unsigned uin = *(const unsigned*)&Xs[cur][384 + n * 32 + kk];
        unsigned urm = *(const unsigned*)&Xs[cur][m * 32 + kk];
        unsigned uim = *(const unsigned*)&Xs[cur][384 + m * 32 + kk];
        float rn0 = ubits(urn << 16), rn1 = ubits(urn & 0xffff0000u);
        float in0 = ubits(uin << 16), in1 = ubits(uin & 0xffff0000u);
        float rm0 = ubits(urm << 16), rm1 = ubits(urm & 0xffff0000u);
        float im0 = ubits(uim << 16), im1 = ubits(uim & 0xffff0000u);
        float v0, v1;
        if (phi) { v0 = in0 * rm0 - rn0 * im0; v1 = in1 * rm1 - rn1 * im1; }
        else     { v0 = rn0 * rm0 + in0 * im0; v1 = rn1 * rm1 + in1 * im1; }
        pk = (unsigned)f2bf(v0) | ((unsigned)f2bf(v1) << 16);
      }
      *(unsigned*)(&Asm_[rl * 40 + kk]) = pk;
    }

    asm volatile("s_waitcnt lgkmcnt(0)" ::: "memory");
    __builtin_amdgcn_s_barrier();
    asm volatile("" ::: "memory");

    short8_t aF[3];
    #pragma unroll
    for (int mi = 0; mi < 3; mi++)
      aF[mi] = *(const short8_t*)(&Asm_[(wm * 48 + mi * 16 + arow) * 40 + aoff]);
    #pragma unroll
    for (int ni = 0; ni < 3; ni++) {
      const int ct = ni * 4 + wn;
      if (ct <= 8) {
        const int brow = ct * 16 + arow;
        const int chp  = g ^ ((brow >> 1) & 3);   // un-swizzle
        short8_t bF = *(const short8_t*)(&Bs[cur][brow * 32 + (chp << 3)]);
        #pragma unroll
        for (int mi = 0; mi < 3; mi++)
          acc[mi][ni] = __builtin_amdgcn_mfma_f32_16x16x32_bf16(aF[mi], bF, acc[mi][ni], 0, 0, 0);
      }
    }

    asm volatile("s_waitcnt lgkmcnt(0) vmcnt(0)" ::: "memory");
    __builtin_amdgcn_s_barrier();
    asm volatile("" ::: "memory");
  }

  // epilogue: D col = lane&15 (tau), row = (lane>>4)*4 + reg
  float* Pz = P + (size_t)phi * PELEMS;
  const int rbase = g << 2;
  #pragma unroll
  for (int ni = 0; ni < 3; ni++) {
    const int ct = ni * 4 + wn;
    if (ct > 8) continue;
    const int tau = ct * 16 + arow;
    if (tau > 128) continue;
    #pragma unroll
    for (int mi = 0; mi < 3; mi++) {
      #pragma unroll
      for (int r = 0; r < 4; r++) {
        int rl = wm * 48 + mi * 16 + rbase + r;
        if (rl < 72) {
          int p = mb * 72 + rl;
          Pz[((size_t)b * 144 + p) * NTAUH + tau] = acc[mi][ni][r];
        }
      }
    }
  }
}

// ---------------- Stage 4: out[b,n,m,o] = P0+P1 at (o<=128 ? (nm,o) : (mn,257-o)) --------
__global__ __launch_bounds__(256) void k_remap(const float* __restrict__ P,
                                               float* __restrict__ out) {
  size_t i = (size_t)blockIdx.x * 256 + threadIdx.x;
  if (i >= (size_t)OUT_ELEMS) return;
  int o = (int)(i % NTAU);
  size_t pp = i / NTAU;
  int p = (int)(pp % 144);
  int b = (int)(pp / 144);
  int n = p / 12, m = p - n * 12;
  int q, t;
  if (o <= 128) { q = p;          t = o; }
  else          { q = m * 12 + n; t = NTAU - o; }
  size_t base = ((size_t)b * 144 + q) * NTAUH + t;
  out[i] = P[base] + P[PELEMS + base];
}

extern "C" void kernel_launch(void* const* d_in, const int* in_sizes, int n_in,
                              void* d_out, int out_size, void* d_ws, size_t ws_size,
                              hipStream_t stream) {
  const float* x = (const float*)d_in[0];
  float* out = (float*)d_out;

  // ws layout (~33 MB): [Tbl 2 phases][Xr][Xi][P 2 phases]
  unsigned short* Tbl = (unsigned short*)d_ws;                // 2*TBLN shorts
  unsigned short* Xr  = Tbl + 2 * TBLN;                       // NROW*NFP
  unsigned short* Xi  = Xr + (size_t)NROW * NFP;              // NROW*NFP
  float* P = (float*)(Xi + (size_t)NROW * NFP);               // 2*PELEMS f32

  k_fft_phat<<<NROW, 512, 0, stream>>>(x, Xr, Xi);
  k_tables<<<(2 * TBLN + 255) / 256, 256, 0, stream>>>(Tbl);
  k_corr<<<dim3(2, NB, 2), 512, 0, stream>>>(Xr, Xi, Tbl, P);
  k_remap<<<(OUT_ELEMS + 255) / 256, 256, 0, stream>>>(P, out);
}

// Round 6
// 170.567 us; speedup vs baseline: 3.3172x; 1.1382x over previous
//
#include <hip/hip_runtime.h>
#include <hip/hip_bf16.h>

#define NB    128
#define NSIG  12
#define KLEN  4096
#define NF    2049          // rfft bins
#define NFP   2080          // padded (65*32)
#define NTAU  257
#define NROW  (NB*NSIG)
#define NSLICE 65           // K slices of 32
#define BROWS 144           // B tile rows (taus 0..128 live, 129..143 zero)
#define TBLN  (NSLICE*BROWS*32)   // shorts per phase table
#define OUT_ELEMS (NB*144*NTAU)

typedef short short8_t __attribute__((ext_vector_type(8)));
typedef float floatx4  __attribute__((ext_vector_type(4)));

__device__ __forceinline__ unsigned short f2bf(float f) {
  union { float f; unsigned u; } v; v.f = f;
  unsigned r = v.u + 0x7FFFu + ((v.u >> 16) & 1u);   // RNE
  return (unsigned short)(r >> 16);
}
__device__ __forceinline__ float ubits(unsigned u) {
  union { unsigned u; float f; } v; v.u = u; return v.f;
}

// async global(16B) -> LDS; dest = wave-uniform base + lane*16
__device__ __forceinline__ void gload16(const unsigned short* g, unsigned short* l) {
  __builtin_amdgcn_global_load_lds((const __attribute__((address_space(1))) unsigned int*)g,
                                   (__attribute__((address_space(3))) unsigned int*)l, 16, 0, 0);
}

// ---------------- Stage 1: radix-4 DIF FFT + PHAT normalize -> bf16 unit spectrum --------
// Natural-order input; DIF leaves X[k] at base-4 digit-reversed position; normalize gathers.
__global__ __launch_bounds__(512) void k_fft_phat(const float* __restrict__ x,
                                                  unsigned short* __restrict__ Xr,
                                                  unsigned short* __restrict__ Xi) {
  __shared__ float re[KLEN];
  __shared__ float im[KLEN];
  const int row = blockIdx.x;          // b*12+n
  const int tid = threadIdx.x;
  const float* xr = x + (size_t)row * KLEN;

  // natural-order coalesced load, contiguous LDS writes
  const float4 z4 = make_float4(0.f, 0.f, 0.f, 0.f);
  #pragma unroll
  for (int q = 0; q < 2; q++) {
    float4 v = ((const float4*)xr)[tid * 2 + q];
    *(float4*)&re[tid * 8 + q * 4] = v;
    *(float4*)&im[tid * 8 + q * 4] = z4;
  }
  __syncthreads();

  // 4 radix-4 DIF stages in LDS: L = 4096, 1024, 256, 64
  #pragma unroll
  for (int s = 0; s < 4; s++) {
    const int lq = 10 - 2 * s;
    const int Q  = 1 << lq;
    const float wconst = -6.2831853071795864f / (float)(4 << lq);
    #pragma unroll
    for (int it = 0; it < 2; it++) {
      const int u = tid + (it << 9);         // 0..1023
      const int j = u & (Q - 1);
      const int p = ((u >> lq) << (lq + 2)) + j;
      float x0r = re[p],         x0i = im[p];
      float x1r = re[p + Q],     x1i = im[p + Q];
      float x2r = re[p + 2 * Q], x2i = im[p + 2 * Q];
      float x3r = re[p + 3 * Q], x3i = im[p + 3 * Q];
      float s1, c1;
      __sincosf(wconst * (float)j, &s1, &c1);
      float c2 = c1 * c1 - s1 * s1, s2 = 2.f * c1 * s1;
      float c3 = c1 * c2 - s1 * s2, s3 = c1 * s2 + s1 * c2;
      float ar = x0r + x2r, ai = x0i + x2i;
      float br = x0r - x2r, bi = x0i - x2i;
      float cr = x1r + x3r, ci = x1i + x3i;
      float dr = x1r - x3r, di = x1i - x3i;
      float t1r = br + di, t1i = bi - dr;     // (b - i d)
      float t2r = ar - cr, t2i = ai - ci;
      float t3r = br - di, t3i = bi + dr;     // (b + i d)
      re[p]         = ar + cr;              im[p]         = ai + ci;
      re[p + Q]     = t1r * c1 - t1i * s1;  im[p + Q]     = t1r * s1 + t1i * c1;
      re[p + 2 * Q] = t2r * c2 - t2i * s2;  im[p + 2 * Q] = t2r * s2 + t2i * c2;
      re[p + 3 * Q] = t3r * c3 - t3i * s3;  im[p + 3 * Q] = t3r * s3 + t3i * c3;
    }
    __syncthreads();
  }

  // fused last two stages (L=16 then L=4) in registers, 16 contiguous points/thread
  if (tid < 256) {
    const int base = tid << 4;
    float R[16], I[16];
    #pragma unroll
    for (int q = 0; q < 4; q++) {
      *(float4*)&R[q * 4] = *(float4*)&re[base + q * 4];
      *(float4*)&I[q * 4] = *(float4*)&im[base + q * 4];
    }
    // L=16, Q=4: W = exp(-i*pi*j/8)
    const float TC[4] = {1.f, 0.92387953251f, 0.70710678119f, 0.38268343236f};
    const float TS[4] = {0.f, -0.38268343236f, -0.70710678119f, -0.92387953251f};
    #pragma unroll
    for (int j = 0; j < 4; j++) {
      float c1 = TC[j], s1 = TS[j];
      float c2 = c1 * c1 - s1 * s1, s2 = 2.f * c1 * s1;
      float c3 = c1 * c2 - s1 * s2, s3 = c1 * s2 + s1 * c2;
      float x0r = R[j],      x0i = I[j];
      float x1r = R[j + 4],  x1i = I[j + 4];
      float x2r = R[j + 8],  x2i = I[j + 8];
      float x3r = R[j + 12], x3i = I[j + 12];
      float ar = x0r + x2r, ai = x0i + x2i;
      float br = x0r - x2r, bi = x0i - x2i;
      float cr = x1r + x3r, ci = x1i + x3i;
      float dr = x1r - x3r, di = x1i - x3i;
      float t1r = br + di, t1i = bi - dr;
      float t2r = ar - cr, t2i = ai - ci;
      float t3r = br - di, t3i = bi + dr;
      R[j]      = ar + cr;             I[j]      = ai + ci;
      R[j + 4]  = t1r * c1 - t1i * s1; I[j + 4]  = t1r * s1 + t1i * c1;
      R[j + 8]  = t2r * c2 - t2i * s2; I[j + 8]  = t2r * s2 + t2i * c2;
      R[j + 12] = t3r * c3 - t3i * s3; I[j + 12] = t3r * s3 + t3i * c3;
    }
    // L=4, Q=1: twiddle-free
    #pragma unroll
    for (int h = 0; h < 4; h++) {
      const int i0 = 4 * h;
      float x0r = R[i0],     x0i = I[i0];
      float x1r = R[i0 + 1], x1i = I[i0 + 1];
      float x2r = R[i0 + 2], x2i = I[i0 + 2];
      float x3r = R[i0 + 3], x3i = I[i0 + 3];
      float ar = x0r + x2r, ai = x0i + x2i;
      float br = x0r - x2r, bi = x0i - x2i;
      float cr = x1r + x3r, ci = x1i + x3i;
      float dr = x1r - x3r, di = x1i - x3i;
      R[i0]     = ar + cr; I[i0]     = ai + ci;
      R[i0 + 1] = br + di; I[i0 + 1] = bi - dr;
      R[i0 + 2] = ar - cr; I[i0 + 2] = ai - ci;
      R[i0 + 3] = br - di; I[i0 + 3] = bi + dr;
    }
    #pragma unroll
    for (int q = 0; q < 4; q++) {
      *(float4*)&re[base + q * 4] = *(float4*)&R[q * 4];
      *(float4*)&im[base + q * 4] = *(float4*)&I[q * 4];
    }
  }
  __syncthreads();

  // PHAT normalize; X[f] sits at digit-reversed-base-4 position
  unsigned short* Xrr = Xr + (size_t)row * NFP;
  unsigned short* Xii = Xi + (size_t)row * NFP;
  for (int f = tid; f < NFP; f += 512) {
    float a = 0.f, bb = 0.f;
    if (f < NF) {
      unsigned rb = __brev((unsigned)f) >> 20;
      int idx = (int)(((rb & 0x555u) << 1) | ((rb >> 1) & 0x555u));
      float rr = re[idx], ii = im[idx];
      float mag = sqrtf(rr * rr + ii * ii) + 1e-12f;
      a  = rr / mag;
      bb = ii / mag;
    }
    Xrr[f] = f2bf(a);
    Xii[f] = f2bf(bb);
  }
}

// ---------------- Stage 2: lag tables, slice-tiled + XOR-swizzled chunk layout ----------
// Tbl[ph][s][row][chp][j] holds logical (row, chl=chp^((row>>1)&3)) value:
//   f = s*32 + chl*8 + j, tau = row;  ph0: w*cos(2pi f tau/K), ph1: -w*sin(...)
__global__ __launch_bounds__(256) void k_tables(unsigned short* __restrict__ Tbl) {
  int e = blockIdx.x * 256 + threadIdx.x;
  if (e >= 2 * TBLN) return;
  int ph = e / TBLN;
  int r  = e - ph * TBLN;
  int s  = r / (BROWS * 32);
  int r2 = r - s * (BROWS * 32);
  int row = r2 >> 5;
  int q   = r2 & 31;
  int chp = q >> 3;
  int j   = q & 7;
  int chl = chp ^ ((row >> 1) & 3);
  int f   = s * 32 + chl * 8 + j;
  float val = 0.f;
  if (row <= 128 && f <= 2048) {
    float wgt = (f == 0 || f == KLEN / 2) ? (1.0f / KLEN) : (2.0f / KLEN);
    int rr = (f * row) & (KLEN - 1);
    float ang = (float)rr * (6.2831853071795864f / KLEN);
    float sn, cs;
    __sincosf(ang, &sn, &cs);
    val = ph ? (-wgt * sn) : (wgt * cs);
  }
  Tbl[e] = f2bf(val);
}

// ---------------- Stage 3: out = Gr·C + Gi·S (both phases per block), direct write -------
// grid (2, 128): mb = pair half (72 rows), b. 512 thr = 8 waves (2M x 4N).
// tile M=96 (72 live), N=144 (9 frags; ct=ni*4+wn, skip ct>8), K-step 32, 65 steps.
// Epilogue writes out[p][tau] and the mirrored out[swap(p)][257-tau] -> no remap kernel.
__global__ __launch_bounds__(512, 2) void k_corr(const unsigned short* __restrict__ Xr,
                                                 const unsigned short* __restrict__ Xi,
                                                 const unsigned short* __restrict__ Tbl,
                                                 float* __restrict__ out) {
  __shared__ alignas(16) unsigned short Xs[2][1024];      // [buf][Xr 12x32 | Xi 12x32]
  __shared__ alignas(16) unsigned short Bs[2][2 * 4608];  // [buf][C 576 chunks | S 576]
  __shared__ alignas(16) unsigned short As[2][96 * 40];   // [phase][row stride 40]

  const int b    = blockIdx.y;
  const int mb   = blockIdx.x;
  const int tid  = threadIdx.x;
  const int w    = tid >> 6;
  const int wm   = w >> 2;            // 0..1
  const int wn   = w & 3;             // 0..3
  const int lane = tid & 63;
  const int arow = lane & 15;
  const int g    = lane >> 4;         // 0..3 (k chunk)
  const int aoff = g << 3;

  floatx4 acc[3][3];
  #pragma unroll
  for (int i = 0; i < 3; i++)
    #pragma unroll
    for (int j = 0; j < 3; j++)
      acc[i][j] = (floatx4){0.f, 0.f, 0.f, 0.f};

  const unsigned short* XrB = Xr + (size_t)b * NSIG * NFP;
  const unsigned short* XiB = Xi + (size_t)b * NSIG * NFP;

  auto bsrc = [&](int cc, size_t so) -> const unsigned short* {
    int tbl = cc >= 576;
    int c = cc - 576 * tbl;
    return Tbl + (size_t)tbl * TBLN + so + (size_t)c * 8;
  };

  auto STAGE = [&](int sl, int nb) {
    const size_t so = (size_t)sl * 4608;
    const int f0n = sl * 32;
    int cc0 = (w << 6) + lane;
    gload16(bsrc(cc0, so), &Bs[nb][(size_t)(w << 6) * 8]);
    int cc1 = 512 + cc0;
    gload16(bsrc(cc1, so), &Bs[nb][(size_t)(512 + (w << 6)) * 8]);
    if (w < 2) {
      int cc2 = 1024 + cc0;
      gload16(bsrc(cc2, so), &Bs[nb][(size_t)(1024 + (w << 6)) * 8]);
    } else if (w == 2) {           // X chunks 0..63: Xr rows 0..11, Xi rows 0..3
      int part = lane >= 48;
      int cc = lane - part * 48;
      const unsigned short* src = (part ? XiB : XrB) + (cc >> 2) * NFP + f0n + ((cc & 3) << 3);
      gload16(src, &Xs[nb][0]);
    } else if (w == 3) {           // X chunks 64..95: Xi rows 4..11
      if (lane < 32) {
        int cc = 16 + lane;
        gload16(XiB + (cc >> 2) * NFP + f0n + ((cc & 3) << 3), &Xs[nb][512]);
      }
    }
  };

  // prologue
  STAGE(0, 0);
  asm volatile("s_waitcnt vmcnt(0)" ::: "memory");
  __builtin_amdgcn_s_barrier();
  asm volatile("" ::: "memory");

  for (int t = 0; t < NSLICE; t++) {
    const int cur = t & 1;
    if (t + 1 < NSLICE) STAGE(t + 1, cur ^ 1);

    // A tiles: Gr and Gi share the X loads/unpacks
    #pragma unroll
    for (int ee = 0; ee < 3; ee++) {
      int e  = tid + (ee << 9);       // 0..1535
      int rl = e >> 4;
      int kk = (e & 15) << 1;
      unsigned pr = 0, pi = 0;
      if (rl < 72) {
        int p = mb * 72 + rl;
        int n = p / 12;
        int m = p - n * 12;
        unsigned urn = *(const unsigned*)&Xs[cur][n * 32 + kk];
        unsigned uin = *(const unsigned*)&Xs[cur][384 + n * 32 + kk];
        unsigned urm = *(const unsigned*)&Xs[cur][m * 32 + kk];
        unsigned uim = *(const unsigned*)&Xs[cur][384 + m * 32 + kk];
        float rn0 = ubits(urn << 16), rn1 = ubits(urn & 0xffff0000u);
        float in0 = ubits(uin << 16), in1 = ubits(uin & 0xffff0000u);
        float rm0 = ubits(urm << 16), rm1 = ubits(urm & 0xffff0000u);
        float im0 = ubits(uim << 16), im1 = ubits(uim & 0xffff0000u);
        float vr0 = rn0 * rm0 + in0 * im0, vr1 = rn1 * rm1 + in1 * im1;
        float vi0 = in0 * rm0 - rn0 * im0, vi1 = in1 * rm1 - rn1 * im1;
        pr = (unsigned)f2bf(vr0) | ((unsigned)f2bf(vr1) << 16);
        pi = (unsigned)f2bf(vi0) | ((unsigned)f2bf(vi1) << 16);
      }
      *(unsigned*)&As[0][rl * 40 + kk] = pr;
      *(unsigned*)&As[1][rl * 40 + kk] = pi;
    }

    asm volatile("s_waitcnt lgkmcnt(0)" ::: "memory");
    __builtin_amdgcn_s_barrier();
    asm volatile("" ::: "memory");

    short8_t aC[3], aS[3];
    #pragma unroll
    for (int mi = 0; mi < 3; mi++) {
      const int ro = (wm * 48 + mi * 16 + arow) * 40 + aoff;
      aC[mi] = *(const short8_t*)&As[0][ro];
      aS[mi] = *(const short8_t*)&As[1][ro];
    }
    #pragma unroll
    for (int ni = 0; ni < 3; ni++) {
      const int ct = ni * 4 + wn;
      if (ct <= 8) {
        const int brow = ct * 16 + arow;
        const int chp  = g ^ ((brow >> 1) & 3);   // un-swizzle
        const unsigned short* bp = &Bs[cur][brow * 32 + (chp << 3)];
        short8_t bC = *(const short8_t*)bp;
        short8_t bS = *(const short8_t*)(bp + 4608);
        #pragma unroll
        for (int mi = 0; mi < 3; mi++) {
          acc[mi][ni] = __builtin_amdgcn_mfma_f32_16x16x32_bf16(aC[mi], bC, acc[mi][ni], 0, 0, 0);
          acc[mi][ni] = __builtin_amdgcn_mfma_f32_16x16x32_bf16(aS[mi], bS, acc[mi][ni], 0, 0, 0);
        }
      }
    }

    asm volatile("s_waitcnt lgkmcnt(0) vmcnt(0)" ::: "memory");
    __builtin_amdgcn_s_barrier();
    asm volatile("" ::: "memory");
  }

  // epilogue: D col = lane&15 (tau), row = (lane>>4)*4 + reg.
  // direct slot (p, tau) plus mirrored slot (swap(p), 257-tau) for tau>=1.
  const int rbase = g << 2;
  #pragma unroll
  for (int ni = 0; ni < 3; ni++) {
    const int ct = ni * 4 + wn;
    if (ct > 8) continue;
    const int tau = ct * 16 + arow;
    if (tau > 128) continue;
    #pragma unroll
    for (int mi = 0; mi < 3; mi++) {
      #pragma unroll
      for (int r = 0; r < 4; r++) {
        int rl = wm * 48 + mi * 16 + rbase + r;
        if (rl < 72) {
          int p = mb * 72 + rl;
          int n = p / 12;
          int m = p - n * 12;
          float val = acc[mi][ni][r];
          out[((size_t)b * 144 + p) * NTAU + tau] = val;
          if (tau > 0)
            out[((size_t)b * 144 + m * 12 + n) * NTAU + (NTAU - tau)] = val;
        }
      }
    }
  }
}

extern "C" void kernel_launch(void* const* d_in, const int* in_sizes, int n_in,
                              void* d_out, int out_size, void* d_ws, size_t ws_size,
                              hipStream_t stream) {
  const float* x = (const float*)d_in[0];
  float* out = (float*)d_out;

  // ws layout (~13.1 MB): [Tbl 2 phases][Xr][Xi]
  unsigned short* Tbl = (unsigned short*)d_ws;                // 2*TBLN shorts
  unsigned short* Xr  = Tbl + 2 * TBLN;                       // NROW*NFP
  unsigned short* Xi  = Xr + (size_t)NROW * NFP;              // NROW*NFP

  k_fft_phat<<<NROW, 512, 0, stream>>>(x, Xr, Xi);
  k_tables<<<(2 * TBLN + 255) / 256, 256, 0, stream>>>(Tbl);
  k_corr<<<dim3(2, NB), 512, 0, stream>>>(Xr, Xi, Tbl, out);
}

// Round 8
// 155.483 us; speedup vs baseline: 3.6391x; 1.0970x over previous
//
#include <hip/hip_runtime.h>
#include <hip/hip_bf16.h>

#define NB    128
#define NSIG  12
#define KLEN  4096
#define NF    2049          // rfft bins
#define NFP   2080          // padded (65*32)
#define NTAU  257
#define NROW  (NB*NSIG)
#define NSLICE 65           // K slices of 32
#define BROWS 144           // B tile rows (taus 0..128 live, 129..143 zero)
#define TBLN  (NSLICE*BROWS*32)   // shorts per phase table
#define OUT_ELEMS (NB*144*NTAU)

// LDS float address map: spreads stride-64 gathers across all 32 banks
#define AP(p) ((p) + ((p) >> 6))

typedef short short8_t __attribute__((ext_vector_type(8)));
typedef float floatx4  __attribute__((ext_vector_type(4)));

__device__ __forceinline__ unsigned short f2bf(float f) {
  union { float f; unsigned u; } v; v.f = f;
  unsigned r = v.u + 0x7FFFu + ((v.u >> 16) & 1u);   // RNE
  return (unsigned short)(r >> 16);
}
__device__ __forceinline__ float ubits(unsigned u) {
  union { unsigned u; float f; } v; v.u = u; return v.f;
}

// async global(16B) -> LDS; dest = wave-uniform base + lane*16
__device__ __forceinline__ void gload16(const unsigned short* g, unsigned short* l) {
  __builtin_amdgcn_global_load_lds((const __attribute__((address_space(1))) unsigned int*)g,
                                   (__attribute__((address_space(3))) unsigned int*)l, 16, 0, 0);
}

// ---------------- Stage 1: radix-4 DIF FFT + PHAT normalize -> bf16 unit spectrum --------
// Natural-order input; DIF leaves X[k] at base-4 digit-reversed position; normalize gathers.
// All LDS accesses go through AP() so the digit-reversed gather is bank-conflict-free.
__global__ __launch_bounds__(512) void k_fft_phat(const float* __restrict__ x,
                                                  unsigned short* __restrict__ Xr,
                                                  unsigned short* __restrict__ Xi) {
  __shared__ float re[KLEN + 64];
  __shared__ float im[KLEN + 64];
  const int row = blockIdx.x;          // b*12+n
  const int tid = threadIdx.x;
  const float* xr = x + (size_t)row * KLEN;

  // natural-order coalesced load (float4 never crosses a 64-float boundary)
  const float4 z4 = make_float4(0.f, 0.f, 0.f, 0.f);
  #pragma unroll
  for (int q = 0; q < 2; q++) {
    int p = tid * 8 + q * 4;
    float4 v = ((const float4*)xr)[tid * 2 + q];
    *(float4*)&re[AP(p)] = v;
    *(float4*)&im[AP(p)] = z4;
  }
  __syncthreads();

  // 4 radix-4 DIF stages in LDS: L = 4096, 1024, 256, 64
  #pragma unroll
  for (int s = 0; s < 4; s++) {
    const int lq = 10 - 2 * s;
    const int Q  = 1 << lq;
    const int Qa = Q + (Q >> 6);
    const float wconst = -6.2831853071795864f / (float)(4 << lq);
    #pragma unroll
    for (int it = 0; it < 2; it++) {
      const int u = tid + (it << 9);         // 0..1023
      const int j = u & (Q - 1);
      const int p0 = AP(((u >> lq) << (lq + 2)) + j);
      float x0r = re[p0],          x0i = im[p0];
      float x1r = re[p0 + Qa],     x1i = im[p0 + Qa];
      float x2r = re[p0 + 2 * Qa], x2i = im[p0 + 2 * Qa];
      float x3r = re[p0 + 3 * Qa], x3i = im[p0 + 3 * Qa];
      float s1, c1;
      __sincosf(wconst * (float)j, &s1, &c1);
      float c2 = c1 * c1 - s1 * s1, s2 = 2.f * c1 * s1;
      float c3 = c1 * c2 - s1 * s2, s3 = c1 * s2 + s1 * c2;
      float ar = x0r + x2r, ai = x0i + x2i;
      float br = x0r - x2r, bi = x0i - x2i;
      float cr = x1r + x3r, ci = x1i + x3i;
      float dr = x1r - x3r, di = x1i - x3i;
      float t1r = br + di, t1i = bi - dr;     // (b - i d)
      float t2r = ar - cr, t2i = ai - ci;
      float t3r = br - di, t3i = bi + dr;     // (b + i d)
      re[p0]          = ar + cr;              im[p0]          = ai + ci;
      re[p0 + Qa]     = t1r * c1 - t1i * s1;  im[p0 + Qa]     = t1r * s1 + t1i * c1;
      re[p0 + 2 * Qa] = t2r * c2 - t2i * s2;  im[p0 + 2 * Qa] = t2r * s2 + t2i * c2;
      re[p0 + 3 * Qa] = t3r * c3 - t3i * s3;  im[p0 + 3 * Qa] = t3r * s3 + t3i * c3;
    }
    __syncthreads();
  }

  // fused last two stages (L=16 then L=4) in registers, 16 contiguous points/thread
  if (tid < 256) {
    const int ab = AP(tid << 4);
    float R[16], I[16];
    #pragma unroll
    for (int q = 0; q < 4; q++) {
      *(float4*)&R[q * 4] = *(float4*)&re[ab + q * 4];
      *(float4*)&I[q * 4] = *(float4*)&im[ab + q * 4];
    }
    // L=16, Q=4: W = exp(-i*pi*j/8)
    const float TC[4] = {1.f, 0.92387953251f, 0.70710678119f, 0.38268343236f};
    const float TS[4] = {0.f, -0.38268343236f, -0.70710678119f, -0.92387953251f};
    #pragma unroll
    for (int j = 0; j < 4; j++) {
      float c1 = TC[j], s1 = TS[j];
      float c2 = c1 * c1 - s1 * s1, s2 = 2.f * c1 * s1;
      float c3 = c1 * c2 - s1 * s2, s3 = c1 * s2 + s1 * c2;
      float x0r = R[j],      x0i = I[j];
      float x1r = R[j + 4],  x1i = I[j + 4];
      float x2r = R[j + 8],  x2i = I[j + 8];
      float x3r = R[j + 12], x3i = I[j + 12];
      float ar = x0r + x2r, ai = x0i + x2i;
      float br = x0r - x2r, bi = x0i - x2i;
      float cr = x1r + x3r, ci = x1i + x3i;
      float dr = x1r - x3r, di = x1i - x3i;
      float t1r = br + di, t1i = bi - dr;
      float t2r = ar - cr, t2i = ai - ci;
      float t3r = br - di, t3i = bi + dr;
      R[j]      = ar + cr;             I[j]      = ai + ci;
      R[j + 4]  = t1r * c1 - t1i * s1; I[j + 4]  = t1r * s1 + t1i * c1;
      R[j + 8]  = t2r * c2 - t2i * s2; I[j + 8]  = t2r * s2 + t2i * c2;
      R[j + 12] = t3r * c3 - t3i * s3; I[j + 12] = t3r * s3 + t3i * c3;
    }
    // L=4, Q=1: twiddle-free
    #pragma unroll
    for (int h = 0; h < 4; h++) {
      const int i0 = 4 * h;
      float x0r = R[i0],     x0i = I[i0];
      float x1r = R[i0 + 1], x1i = I[i0 + 1];
      float x2r = R[i0 + 2], x2i = I[i0 + 2];
      float x3r = R[i0 + 3], x3i = I[i0 + 3];
      float ar = x0r + x2r, ai = x0i + x2i;
      float br = x0r - x2r, bi = x0i - x2i;
      float cr = x1r + x3r, ci = x1i + x3i;
      float dr = x1r - x3r, di = x1i - x3i;
      R[i0]     = ar + cr; I[i0]     = ai + ci;
      R[i0 + 1] = br + di; I[i0 + 1] = bi - dr;
      R[i0 + 2] = ar - cr; I[i0 + 2] = ai - ci;
      R[i0 + 3] = br - di; I[i0 + 3] = bi + dr;
    }
    #pragma unroll
    for (int q = 0; q < 4; q++) {
      *(float4*)&re[ab + q * 4] = *(float4*)&R[q * 4];
      *(float4*)&im[ab + q * 4] = *(float4*)&I[q * 4];
    }
  }
  __syncthreads();

  // PHAT normalize; X[f] sits at digit-reversed-base-4 position (AP-mapped: conflict-free)
  unsigned short* Xrr = Xr + (size_t)row * NFP;
  unsigned short* Xii = Xi + (size_t)row * NFP;
  for (int f = tid; f < NFP; f += 512) {
    float a = 0.f, bb = 0.f;
    if (f < NF) {
      unsigned rb = __brev((unsigned)f) >> 20;
      int idx = (int)(((rb & 0x555u) << 1) | ((rb >> 1) & 0x555u));
      int rd = AP(idx);
      float rr = re[rd], ii = im[rd];
      float mag = sqrtf(rr * rr + ii * ii) + 1e-12f;
      a  = rr / mag;
      bb = ii / mag;
    }
    Xrr[f] = f2bf(a);
    Xii[f] = f2bf(bb);
  }
}

// ---------------- Stage 2: lag tables, slice-tiled + XOR-swizzled chunk layout ----------
__global__ __launch_bounds__(256) void k_tables(unsigned short* __restrict__ Tbl) {
  int e = blockIdx.x * 256 + threadIdx.x;
  if (e >= 2 * TBLN) return;
  int ph = e / TBLN;
  int r  = e - ph * TBLN;
  int s  = r / (BROWS * 32);
  int r2 = r - s * (BROWS * 32);
  int row = r2 >> 5;
  int q   = r2 & 31;
  int chp = q >> 3;
  int j   = q & 7;
  int chl = chp ^ ((row >> 1) & 3);
  int f   = s * 32 + chl * 8 + j;
  float val = 0.f;
  if (row <= 128 && f <= 2048) {
    float wgt = (f == 0 || f == KLEN / 2) ? (1.0f / KLEN) : (2.0f / KLEN);
    int rr = (f * row) & (KLEN - 1);
    float ang = (float)rr * (6.2831853071795864f / KLEN);
    float sn, cs;
    __sincosf(ang, &sn, &cs);
    val = ph ? (-wgt * sn) : (wgt * cs);
  }
  Tbl[e] = f2bf(val);
}

// ---------------- Stage 3: out = Gr·C + Gi·S (both phases per block), direct write -------
// grid (4, 128): mb = quarter of pairs (36 rows), b. 512 thr = 8 waves (2M x 4N).
// tile M=48 (36 live; wm0: frags 0-1, wm1: frag 2), N=144 (9 frags), K-step 32, 65 steps.
__global__ __launch_bounds__(512, 4) void k_corr(const unsigned short* __restrict__ Xr,
                                                 const unsigned short* __restrict__ Xi,
                                                 const unsigned short* __restrict__ Tbl,
                                                 float* __restrict__ out) {
  __shared__ alignas(16) unsigned short Xs[2][1024];      // [buf][Xr 12x32 | Xi 12x32]
  __shared__ alignas(16) unsigned short Bs[2][2 * 4608];  // [buf][C 576 chunks | S 576]
  __shared__ alignas(16) unsigned short As[2][48 * 40];   // [phase][row stride 40]

  const int b    = blockIdx.y;
  const int mb   = blockIdx.x;
  const int tid  = threadIdx.x;
  const int w    = tid >> 6;
  const int wm   = w >> 2;            // 0..1
  const int wn   = w & 3;             // 0..3
  const int lane = tid & 63;
  const int arow = lane & 15;
  const int g    = lane >> 4;         // 0..3 (k chunk)
  const int aoff = g << 3;
  const int nmf  = (wm == 0) ? 2 : 1; // M-frags owned by this wave

  floatx4 acc[2][3];
  #pragma unroll
  for (int i = 0; i < 2; i++)
    #pragma unroll
    for (int j = 0; j < 3; j++)
      acc[i][j] = (floatx4){0.f, 0.f, 0.f, 0.f};

  const unsigned short* XrB = Xr + (size_t)b * NSIG * NFP;
  const unsigned short* XiB = Xi + (size_t)b * NSIG * NFP;

  auto bsrc = [&](int cc, size_t so) -> const unsigned short* {
    int tbl = cc >= 576;
    int c = cc - 576 * tbl;
    return Tbl + (size_t)tbl * TBLN + so + (size_t)c * 8;
  };

  auto STAGE = [&](int sl, int nb) {
    const size_t so = (size_t)sl * 4608;
    const int f0n = sl * 32;
    int cc0 = (w << 6) + lane;
    gload16(bsrc(cc0, so), &Bs[nb][(size_t)(w << 6) * 8]);
    int cc1 = 512 + cc0;
    gload16(bsrc(cc1, so), &Bs[nb][(size_t)(512 + (w << 6)) * 8]);
    if (w < 2) {
      int cc2 = 1024 + cc0;
      gload16(bsrc(cc2, so), &Bs[nb][(size_t)(1024 + (w << 6)) * 8]);
    } else if (w == 2) {           // X chunks 0..63: Xr rows 0..11, Xi rows 0..3
      int part = lane >= 48;
      int cc = lane - part * 48;
      const unsigned short* src = (part ? XiB : XrB) + (cc >> 2) * NFP + f0n + ((cc & 3) << 3);
      gload16(src, &Xs[nb][0]);
    } else if (w == 3) {           // X chunks 64..95: Xi rows 4..11
      if (lane < 32) {
        int cc = 16 + lane;
        gload16(XiB + (cc >> 2) * NFP + f0n + ((cc & 3) << 3), &Xs[nb][512]);
      }
    }
  };

  // prologue
  STAGE(0, 0);
  asm volatile("s_waitcnt vmcnt(0)" ::: "memory");
  __builtin_amdgcn_s_barrier();
  asm volatile("" ::: "memory");

  for (int t = 0; t < NSLICE; t++) {
    const int cur = t & 1;
    if (t + 1 < NSLICE) STAGE(t + 1, cur ^ 1);

    // A tiles: Gr and Gi share the X loads/unpacks. 48 rows x 16 kk-pairs = 768 items.
    #pragma unroll
    for (int ee = 0; ee < 2; ee++) {
      int e = tid + (ee << 9);        // 0..1023
      if (e < 768) {
        int rl = e >> 4;              // 0..47
        int kk = (e & 15) << 1;
        unsigned pr = 0, pi = 0;
        if (rl < 36) {
          int p = mb * 36 + rl;
          int n = p / 12;
          int m = p - n * 12;
          unsigned urn = *(const unsigned*)&Xs[cur][n * 32 + kk];
          unsigned uin = *(const unsigned*)&Xs[cur][384 + n * 32 + kk];
          unsigned urm = *(const unsigned*)&Xs[cur][m * 32 + kk];
          unsigned uim = *(const unsigned*)&Xs[cur][384 + m * 32 + kk];
          float rn0 = ubits(urn << 16), rn1 = ubits(urn & 0xffff0000u);
          float in0 = ubits(uin << 16), in1 = ubits(uin & 0xffff0000u);
          float rm0 = ubits(urm << 16), rm1 = ubits(urm & 0xffff0000u);
          float im0 = ubits(uim << 16), im1 = ubits(uim & 0xffff0000u);
          float vr0 = rn0 * rm0 + in0 * im0, vr1 = rn1 * rm1 + in1 * im1;
          float vi0 = in0 * rm0 - rn0 * im0, vi1 = in1 * rm1 - rn1 * im1;
          pr = (unsigned)f2bf(vr0) | ((unsigned)f2bf(vr1) << 16);
          pi = (unsigned)f2bf(vi0) | ((unsigned)f2bf(vi1) << 16);
        }
        *(unsigned*)&As[0][rl * 40 + kk] = pr;
        *(unsigned*)&As[1][rl * 40 + kk] = pi;
      }
    }

    asm volatile("s_waitcnt lgkmcnt(0)" ::: "memory");
    __builtin_amdgcn_s_barrier();
    asm volatile("" ::: "memory");

    short8_t aC[2], aS[2];
    #pragma unroll
    for (int mi = 0; mi < 2; mi++)
      if (mi < nmf) {
        const int ro = (wm * 32 + mi * 16 + arow) * 40 + aoff;
        aC[mi] = *(const short8_t*)&As[0][ro];
        aS[mi] = *(const short8_t*)&As[1][ro];
      }
    #pragma unroll
    for (int ni = 0; ni < 3; ni++) {
      const int ct = ni * 4 + wn;
      if (ct <= 8) {
        const int brow = ct * 16 + arow;
        const int chp  = g ^ ((brow >> 1) & 3);   // un-swizzle
        const unsigned short* bp = &Bs[cur][brow * 32 + (chp << 3)];
        short8_t bC = *(const short8_t*)bp;
        short8_t bS = *(const short8_t*)(bp + 4608);
        #pragma unroll
        for (int mi = 0; mi < 2; mi++)
          if (mi < nmf) {
            acc[mi][ni] = __builtin_amdgcn_mfma_f32_16x16x32_bf16(aC[mi], bC, acc[mi][ni], 0, 0, 0);
            acc[mi][ni] = __builtin_amdgcn_mfma_f32_16x16x32_bf16(aS[mi], bS, acc[mi][ni], 0, 0, 0);
          }
      }
    }

    asm volatile("s_waitcnt lgkmcnt(0) vmcnt(0)" ::: "memory");
    __builtin_amdgcn_s_barrier();
    asm volatile("" ::: "memory");
  }

  // epilogue: D col = lane&15 (tau), row = (lane>>4)*4 + reg.
  // direct slot (p, tau) plus mirrored slot (swap(p), 257-tau) for tau>=1.
  const int rbase = g << 2;
  #pragma unroll
  for (int ni = 0; ni < 3; ni++) {
    const int ct = ni * 4 + wn;
    if (ct > 8) continue;
    const int tau = ct * 16 + arow;
    if (tau > 128) continue;
    #pragma unroll
    for (int mi = 0; mi < 2; mi++) {
      if (mi >= nmf) continue;
      #pragma unroll
      for (int r = 0; r < 4; r++) {
        int rl = wm * 32 + mi * 16 + rbase + r;
        if (rl < 36) {
          int p = mb * 36 + rl;
          int n = p / 12;
          int m = p - n * 12;
          float val = acc[mi][ni][r];
          out[((size_t)b * 144 + p) * NTAU + tau] = val;
          if (tau > 0)
            out[((size_t)b * 144 + m * 12 + n) * NTAU + (NTAU - tau)] = val;
        }
      }
    }
  }
}

extern "C" void kernel_launch(void* const* d_in, const int* in_sizes, int n_in,
                              void* d_out, int out_size, void* d_ws, size_t ws_size,
                              hipStream_t stream) {
  const float* x = (const float*)d_in[0];
  float* out = (float*)d_out;

  // ws layout (~13.1 MB): [Tbl 2 phases][Xr][Xi]
  unsigned short* Tbl = (unsigned short*)d_ws;                // 2*TBLN shorts
  unsigned short* Xr  = Tbl + 2 * TBLN;                       // NROW*NFP
  unsigned short* Xi  = Xr + (size_t)NROW * NFP;              // NROW*NFP

  k_fft_phat<<<NROW, 512, 0, stream>>>(x, Xr, Xi);
  k_tables<<<(2 * TBLN + 255) / 256, 256, 0, stream>>>(Tbl);
  k_corr<<<dim3(4, NB), 512, 0, stream>>>(Xr, Xi, Tbl, out);
}